// Round 2
// baseline (381.743 us; speedup 1.0000x reference)
//
#include <hip/hip_runtime.h>

#define N_POINTS 500000
#define N_W      128
#define N_OFF    50

// Kernel 1: accumulate Csum[w] = sum_n cos(2*pi*d_n/w) * tid[n,w]
//           Ssum[w] = sum_n sin(...) * tid[n,w]
// Block = 256 threads; lane_w = t&31 indexes a float4 of wavelengths,
// rg = t>>5 picks a row group. Each block-iteration covers 16 consecutive
// rows (two row-sets of 8), giving each lane TWO independent float4 loads
// in flight per iteration. 500000 % 16 == 0 -> exact coverage.
__global__ __launch_bounds__(256, 8) void cs_accum(
    const float* __restrict__ xy,
    const float* __restrict__ tid,
    const float* __restrict__ center,
    const float* __restrict__ wavelength,
    float* __restrict__ sums)   // [0..127]=Csum, [128..255]=Ssum
{
    const int t = threadIdx.x;
    const int lane_w = t & 31;   // float4 column index
    const int rg     = t >> 5;   // 0..7 row-in-tile

    const float cx = center[0];
    const float cy = center[1];

    const float4 wl = ((const float4*)wavelength)[lane_w];
    float invw[4];
    invw[0] = 1.0f / wl.x;
    invw[1] = 1.0f / wl.y;
    invw[2] = 1.0f / wl.z;
    invw[3] = 1.0f / wl.w;

    float accC[4] = {0.f, 0.f, 0.f, 0.f};
    float accS[4] = {0.f, 0.f, 0.f, 0.f};

    const int stride = gridDim.x * 16;
    for (int row0 = blockIdx.x * 16; row0 < N_POINTS; row0 += stride) {
        const int rowA = row0 + rg;
        const int rowB = row0 + 8 + rg;

        // Issue both loads (independent) before any dependent compute.
        const float4 vA = ((const float4*)tid)[rowA * (N_W / 4) + lane_w];
        const float4 vB = ((const float4*)tid)[rowB * (N_W / 4) + lane_w];
        const float2 pA = ((const float2*)xy)[rowA];
        const float2 pB = ((const float2*)xy)[rowB];

        const float dxA = pA.x - cx, dyA = pA.y - cy;
        const float dxB = pB.x - cx, dyB = pB.y - cy;
        const float dA = sqrtf(fmaf(dxA, dxA, dyA * dyA));
        const float dB = sqrtf(fmaf(dxB, dxB, dyB * dyB));

        const float tvA[4] = {vA.x, vA.y, vA.z, vA.w};
        const float tvB[4] = {vB.x, vB.y, vB.z, vB.w};

#pragma unroll
        for (int i = 0; i < 4; ++i) {
            float rA = dA * invw[i];
            rA = rA - floorf(rA);
            accS[i] = fmaf(__builtin_amdgcn_sinf(rA), tvA[i], accS[i]);
            accC[i] = fmaf(__builtin_amdgcn_cosf(rA), tvA[i], accC[i]);
            float rB = dB * invw[i];
            rB = rB - floorf(rB);
            accS[i] = fmaf(__builtin_amdgcn_sinf(rB), tvB[i], accS[i]);
            accC[i] = fmaf(__builtin_amdgcn_cosf(rB), tvB[i], accC[i]);
        }
    }

    // Block reduction over the 8 row-groups, then one atomic per (w, C/S).
    __shared__ float red[2][8][N_W];
    const int wbase = lane_w * 4;
#pragma unroll
    for (int i = 0; i < 4; ++i) {
        red[0][rg][wbase + i] = accC[i];
        red[1][rg][wbase + i] = accS[i];
    }
    __syncthreads();
    if (t < N_W) {
        float sc = 0.f, ss = 0.f;
#pragma unroll
        for (int g = 0; g < 8; ++g) {
            sc += red[0][g][t];
            ss += red[1][g][t];
        }
        atomicAdd(&sums[t], sc);
        atomicAdd(&sums[N_W + t], ss);
    }
}

// Kernel 2: C = Csum/N, S = Ssum/N; m[w] = max_j C*cos(o_j) - S*sin(o_j),
// o_j = 2*pi*j/49; out = -sum_w m[w].
__global__ __launch_bounds__(128) void finalize(
    const float* __restrict__ sums, float* __restrict__ out)
{
    __shared__ float red[N_W];
    const int w = threadIdx.x;
    const float invN = 1.0f / (float)N_POINTS;
    const float C = sums[w] * invN;
    const float S = sums[N_W + w] * invN;

    float m = -3.0e38f;
#pragma unroll
    for (int j = 0; j < N_OFF; ++j) {
        float rev = (float)j * (1.0f / 49.0f);  // offsets/(2*pi) = j/49
        rev = rev - floorf(rev);
        const float v = C * __builtin_amdgcn_cosf(rev)
                      - S * __builtin_amdgcn_sinf(rev);
        m = fmaxf(m, v);
    }
    red[w] = m;
    __syncthreads();
    for (int step = 64; step > 0; step >>= 1) {
        if (w < step) red[w] += red[w + step];
        __syncthreads();
    }
    if (w == 0) out[0] = -red[0];
}

extern "C" void kernel_launch(void* const* d_in, const int* in_sizes, int n_in,
                              void* d_out, int out_size, void* d_ws, size_t ws_size,
                              hipStream_t stream) {
    const float* xy         = (const float*)d_in[0];
    const float* tid        = (const float*)d_in[1];
    const float* center     = (const float*)d_in[2];
    const float* wavelength = (const float*)d_in[3];
    float* sums = (float*)d_ws;   // 256 floats = 1 KB
    float* out  = (float*)d_out;

    // ws is poisoned to 0xAA before every timed launch -> zero it each call.
    hipMemsetAsync(d_ws, 0, 2 * N_W * sizeof(float), stream);

    // 4096 blocks, 16 rows per block-iteration; 8 blocks/CU resident.
    cs_accum<<<4096, 256, 0, stream>>>(xy, tid, center, wavelength, sums);
    finalize<<<1, N_W, 0, stream>>>(sums, out);
}

// Round 3
// 352.442 us; speedup vs baseline: 1.0831x; 1.0831x over previous
//
#include <hip/hip_runtime.h>

#define N_POINTS 500000
#define N_W      128
#define N_OFF    50
#define ROWS_PER_CHUNK 32
#define CHUNKS  (N_POINTS / ROWS_PER_CHUNK)   // 15625, exact
#define N_REP   16                             // atomic shard replicas

// Kernel 1: Csum[w] = sum_n cos(2*pi*d_n/w)*tid[n,w], Ssum likewise.
// Block = 256 threads; lane_w = t&31 picks a float4 of wavelengths,
// rg = t>>5 picks a row slot. Each chunk = 32 consecutive rows; each lane
// processes rows {rg, rg+8, rg+16, rg+24} -> 4 independent float4 loads in
// flight, plus the NEXT chunk's 4 loads are issued before computing the
// current chunk (manual prefetch) -> 8 loads deep per wave.
__global__ __launch_bounds__(256) void cs_accum(
    const float* __restrict__ xy,
    const float* __restrict__ tid,
    const float* __restrict__ center,
    const float* __restrict__ wavelength,
    float* __restrict__ sums)   // [N_REP][256]: per-replica {C[128], S[128]}
{
    const int t = threadIdx.x;
    const int lane_w = t & 31;
    const int rg     = t >> 5;

    const float cx = center[0];
    const float cy = center[1];

    const float4 wl = ((const float4*)wavelength)[lane_w];
    float invw[4];
    invw[0] = 1.0f / wl.x;
    invw[1] = 1.0f / wl.y;
    invw[2] = 1.0f / wl.z;
    invw[3] = 1.0f / wl.w;

    float accC[4] = {0.f, 0.f, 0.f, 0.f};
    float accS[4] = {0.f, 0.f, 0.f, 0.f};

    const int stride = gridDim.x;
    int c = blockIdx.x;            // grid (2048) <= CHUNKS, so c valid

    float4 tv[4];
    float2 p[4];
    {
        const int base = c * ROWS_PER_CHUNK + rg;
#pragma unroll
        for (int r = 0; r < 4; ++r) {
            const int row = base + 8 * r;
            tv[r] = ((const float4*)tid)[row * (N_W / 4) + lane_w];
            p[r]  = ((const float2*)xy)[row];
        }
    }

    for (;;) {
        const int cn = c + stride;
        const bool have_next = (cn < CHUNKS);
        float4 ntv[4];
        float2 np[4];
        if (have_next) {
            const int base = cn * ROWS_PER_CHUNK + rg;
#pragma unroll
            for (int r = 0; r < 4; ++r) {
                const int row = base + 8 * r;
                ntv[r] = ((const float4*)tid)[row * (N_W / 4) + lane_w];
                np[r]  = ((const float2*)xy)[row];
            }
        }

        // compute current chunk
#pragma unroll
        for (int r = 0; r < 4; ++r) {
            const float dx = p[r].x - cx;
            const float dy = p[r].y - cy;
            const float d  = sqrtf(fmaf(dx, dx, dy * dy));
            const float tvr[4] = {tv[r].x, tv[r].y, tv[r].z, tv[r].w};
#pragma unroll
            for (int i = 0; i < 4; ++i) {
                float rr = d * invw[i];
                rr = rr - floorf(rr);                       // revolutions
                accS[i] = fmaf(__builtin_amdgcn_sinf(rr), tvr[i], accS[i]);
                accC[i] = fmaf(__builtin_amdgcn_cosf(rr), tvr[i], accC[i]);
            }
        }

        if (!have_next) break;
#pragma unroll
        for (int r = 0; r < 4; ++r) { tv[r] = ntv[r]; p[r] = np[r]; }
        c = cn;
    }

    // Block reduction over 8 row-groups, then sharded atomics.
    __shared__ float red[2][8][N_W];
    const int wbase = lane_w * 4;
#pragma unroll
    for (int i = 0; i < 4; ++i) {
        red[0][rg][wbase + i] = accC[i];
        red[1][rg][wbase + i] = accS[i];
    }
    __syncthreads();
    if (t < N_W) {
        float sc = 0.f, ss = 0.f;
#pragma unroll
        for (int g = 0; g < 8; ++g) {
            sc += red[0][g][t];
            ss += red[1][g][t];
        }
        const int rep = blockIdx.x & (N_REP - 1);
        atomicAdd(&sums[rep * 256 + t], sc);
        atomicAdd(&sums[rep * 256 + N_W + t], ss);
    }
}

// Kernel 2: fold replicas, C=Csum/N, S=Ssum/N; m[w]=max_j C*cos(o)-S*sin(o);
// out = -sum_w m[w].
__global__ __launch_bounds__(256) void finalize(
    const float* __restrict__ sums, float* __restrict__ out)
{
    __shared__ float cs[256];
    __shared__ float red[N_W];
    const int t = threadIdx.x;

    float v = 0.f;
#pragma unroll
    for (int r = 0; r < N_REP; ++r) v += sums[r * 256 + t];
    cs[t] = v * (1.0f / (float)N_POINTS);
    __syncthreads();

    if (t < N_W) {
        const float C = cs[t];
        const float S = cs[N_W + t];
        float m = -3.0e38f;
#pragma unroll
        for (int j = 0; j < N_OFF; ++j) {
            float rev = (float)j * (1.0f / 49.0f);   // offsets/(2*pi) = j/49
            rev = rev - floorf(rev);
            const float val = C * __builtin_amdgcn_cosf(rev)
                            - S * __builtin_amdgcn_sinf(rev);
            m = fmaxf(m, val);
        }
        red[t] = m;
    }
    __syncthreads();
    for (int step = 64; step > 0; step >>= 1) {
        if (t < step) red[t] += red[t + step];
        __syncthreads();
    }
    if (t == 0) out[0] = -red[0];
}

extern "C" void kernel_launch(void* const* d_in, const int* in_sizes, int n_in,
                              void* d_out, int out_size, void* d_ws, size_t ws_size,
                              hipStream_t stream) {
    const float* xy         = (const float*)d_in[0];
    const float* tid        = (const float*)d_in[1];
    const float* center     = (const float*)d_in[2];
    const float* wavelength = (const float*)d_in[3];
    float* sums = (float*)d_ws;   // N_REP * 256 floats = 16 KB
    float* out  = (float*)d_out;

    // ws is poisoned to 0xAA before every timed launch -> zero it each call.
    hipMemsetAsync(d_ws, 0, N_REP * 256 * sizeof(float), stream);

    cs_accum<<<2048, 256, 0, stream>>>(xy, tid, center, wavelength, sums);
    finalize<<<1, 256, 0, stream>>>(sums, out);
}

// Round 5
// 332.891 us; speedup vs baseline: 1.1468x; 1.0587x over previous
//
#include <hip/hip_runtime.h>

#define N_POINTS 500000
#define N_W      128
#define N_OFF    50
#define ROWS_PER_CHUNK 32
#define CHUNKS  (N_POINTS / ROWS_PER_CHUNK)   // 15625, exact
#define N_REP   32                             // atomic shard replicas
#define GRID    1792

// Native clang vector types: __builtin_nontemporal_load requires these
// (HIP_vector_type wrappers are rejected).
typedef float fx4 __attribute__((ext_vector_type(4)));
typedef float fx2 __attribute__((ext_vector_type(2)));

// Load one chunk's worth of per-lane data: 4 tid float4s (nontemporal,
// zero-reuse stream) + 4 xy float2s (broadcast across lane_w, L2-hot).
__device__ __forceinline__ void load_chunk(
    const fx4* __restrict__ tid4, const fx2* __restrict__ xy2,
    int chunk, int rg, int lane_w, fx4 tv[4], fx2 p[4])
{
    const int base = chunk * ROWS_PER_CHUNK + rg;
#pragma unroll
    for (int r = 0; r < 4; ++r) {
        const int row = base + 8 * r;
        tv[r] = __builtin_nontemporal_load(&tid4[row * (N_W / 4) + lane_w]);
        p[r]  = xy2[row];
    }
}

__device__ __forceinline__ void compute_chunk(
    const fx4 tv[4], const fx2 p[4],
    float cx, float cy, const float invw[4],
    float accC[4], float accS[4])
{
#pragma unroll
    for (int r = 0; r < 4; ++r) {
        const float dx = p[r].x - cx;
        const float dy = p[r].y - cy;
        const float d  = sqrtf(fmaf(dx, dx, dy * dy));
        const float tvr[4] = {tv[r].x, tv[r].y, tv[r].z, tv[r].w};
#pragma unroll
        for (int i = 0; i < 4; ++i) {
            // revolutions: phase/(2*pi) = d / wavelength
            const float rr = __builtin_amdgcn_fractf(d * invw[i]);
            accS[i] = fmaf(__builtin_amdgcn_sinf(rr), tvr[i], accS[i]);
            accC[i] = fmaf(__builtin_amdgcn_cosf(rr), tvr[i], accC[i]);
        }
    }
}

// Csum[w] = sum_n cos(2*pi*d_n/w)*tid[n,w]; Ssum likewise.
// Block = 256; lane_w = t&31 (float4 column), rg = t>>5 (row slot).
// Chunk = 32 consecutive rows; lane handles rows {rg, rg+8, rg+16, rg+24}.
// Ping-pong prefetch (unrolled x2, no register moves): up to 8 tid loads
// in flight per lane while computing the previous chunk.
__global__ __launch_bounds__(256) void cs_accum(
    const float* __restrict__ xy,
    const float* __restrict__ tid,
    const float* __restrict__ center,
    const float* __restrict__ wavelength,
    float* __restrict__ sums)   // [N_REP][256]: {C[128], S[128]} per replica
{
    const int t = threadIdx.x;
    const int lane_w = t & 31;
    const int rg     = t >> 5;

    const float cx = center[0];
    const float cy = center[1];

    const fx4 wl = ((const fx4*)wavelength)[lane_w];
    float invw[4] = {1.0f / wl.x, 1.0f / wl.y, 1.0f / wl.z, 1.0f / wl.w};

    float accC[4] = {0.f, 0.f, 0.f, 0.f};
    float accS[4] = {0.f, 0.f, 0.f, 0.f};

    const fx4* tid4 = (const fx4*)tid;
    const fx2* xy2  = (const fx2*)xy;
    const int stride = gridDim.x;

    fx4 tvA[4], tvB[4];
    fx2 pA[4], pB[4];

    int c = blockIdx.x;                       // GRID < CHUNKS: always valid
    load_chunk(tid4, xy2, c, rg, lane_w, tvA, pA);

    for (;;) {
        const int c1 = c + stride;
        const bool h1 = (c1 < CHUNKS);
        if (h1) load_chunk(tid4, xy2, c1, rg, lane_w, tvB, pB);
        compute_chunk(tvA, pA, cx, cy, invw, accC, accS);
        if (!h1) break;

        const int c2 = c1 + stride;
        const bool h2 = (c2 < CHUNKS);
        if (h2) load_chunk(tid4, xy2, c2, rg, lane_w, tvA, pA);
        compute_chunk(tvB, pB, cx, cy, invw, accC, accS);
        if (!h2) break;

        c = c2;
    }

    // Block reduction over 8 row-groups, then sharded atomics.
    __shared__ float red[2][8][N_W];
    const int wbase = lane_w * 4;
#pragma unroll
    for (int i = 0; i < 4; ++i) {
        red[0][rg][wbase + i] = accC[i];
        red[1][rg][wbase + i] = accS[i];
    }
    __syncthreads();
    if (t < N_W) {
        float sc = 0.f, ss = 0.f;
#pragma unroll
        for (int g = 0; g < 8; ++g) {
            sc += red[0][g][t];
            ss += red[1][g][t];
        }
        const int rep = blockIdx.x & (N_REP - 1);
        atomicAdd(&sums[rep * 256 + t], sc);
        atomicAdd(&sums[rep * 256 + N_W + t], ss);
    }
}

// Fold replicas, C=Csum/N, S=Ssum/N; m[w]=max_j C*cos(o_j)-S*sin(o_j);
// out = -sum_w m[w].
__global__ __launch_bounds__(256) void finalize(
    const float* __restrict__ sums, float* __restrict__ out)
{
    __shared__ float cs[256];
    __shared__ float red[N_W];
    const int t = threadIdx.x;

    float v = 0.f;
#pragma unroll
    for (int r = 0; r < N_REP; ++r) v += sums[r * 256 + t];
    cs[t] = v * (1.0f / (float)N_POINTS);
    __syncthreads();

    if (t < N_W) {
        const float C = cs[t];
        const float S = cs[N_W + t];
        float m = -3.0e38f;
#pragma unroll
        for (int j = 0; j < N_OFF; ++j) {
            const float rev = __builtin_amdgcn_fractf((float)j * (1.0f / 49.0f));
            const float val = C * __builtin_amdgcn_cosf(rev)
                            - S * __builtin_amdgcn_sinf(rev);
            m = fmaxf(m, val);
        }
        red[t] = m;
    }
    __syncthreads();
    for (int step = 64; step > 0; step >>= 1) {
        if (t < step) red[t] += red[t + step];
        __syncthreads();
    }
    if (t == 0) out[0] = -red[0];
}

extern "C" void kernel_launch(void* const* d_in, const int* in_sizes, int n_in,
                              void* d_out, int out_size, void* d_ws, size_t ws_size,
                              hipStream_t stream) {
    const float* xy         = (const float*)d_in[0];
    const float* tid        = (const float*)d_in[1];
    const float* center     = (const float*)d_in[2];
    const float* wavelength = (const float*)d_in[3];
    float* sums = (float*)d_ws;   // N_REP * 256 floats = 32 KB
    float* out  = (float*)d_out;

    // ws is poisoned to 0xAA before every timed launch -> zero it each call.
    (void)hipMemsetAsync(d_ws, 0, N_REP * 256 * sizeof(float), stream);

    cs_accum<<<GRID, 256, 0, stream>>>(xy, tid, center, wavelength, sums);
    finalize<<<1, 256, 0, stream>>>(sums, out);
}